// Round 8
// baseline (549.666 us; speedup 1.0000x reference)
//
#include <hip/hip_runtime.h>
#include <math.h>

#define N_NODES 2048
#define BATCH   64
#define DIN     2
#define DOUT    64
#define CIN     66     // DIN + DOUT
#define CP      68     // padded channel count (GEMM col blocking)
#define D_EMB   10
#define GOUT    128    // gate output channels (2*DOUT)
#define NCOLS   (BATCH*CP)   // 4352, GEMM N dimension
#define MK      2048         // GEMM K
#define KPAD    136          // wpT row pitch
#define INP     160          // IN row pitch (bf16 elems): [0,1]=unused [2,65]=zs [66,133]=AG [134,159]=0
#define WHALF   20480        // bytes per hi (or lo) fragment half-blob (64o x 160k bf16)
#define WBLOB   40960        // hi+lo per (node, o-half)

typedef __attribute__((ext_vector_type(8))) short bf16x8;
typedef __attribute__((ext_vector_type(8))) unsigned short u16x8;
typedef __attribute__((ext_vector_type(4))) float f32x4;

__device__ __forceinline__ unsigned short f2bf_rn(float f) {
    unsigned u = __builtin_bit_cast(unsigned, f);
    unsigned r = u + 0x7FFFu + ((u >> 16) & 1u);   // RNE
    return (unsigned short)(r >> 16);
}
__device__ __forceinline__ float bf2f(unsigned short h) {
    unsigned u = ((unsigned)h) << 16;
    return __builtin_bit_cast(float, u);
}

__device__ __forceinline__ void gload_lds16(const void* g, void* l) {
    __builtin_amdgcn_global_load_lds(
        (const __attribute__((address_space(1))) unsigned int*)g,
        (__attribute__((address_space(3))) unsigned int*)l, 16, 0, 0);
}

// Fragment-layout address inside a 20 KB half-blob: [strip4][kt5][row16][sl4]x16B,
// XOR swizzle spreads the 64B rows across banks (uniform 2-way on b128 reads).
__device__ __forceinline__ int frag_addr(int strip, int kt, int row, int slice) {
    const int byte = ((strip * 5 + kt) * 16 + row) * 64 + slice * 16;
    return byte ^ ((row & 7) << 4);
}

// ---------------------------------------------------------------------------
// Kernel 0: wpT[d][o][kp] = wp[d][kp][o], kp padded to 136 with zeros.
__global__ __launch_bounds__(256) void transpose_pool_kernel(
    const float* __restrict__ wp, float* __restrict__ wpT, int OC, int total)
{
    const int idx = blockIdx.x * 256 + threadIdx.x;
    if (idx >= total) return;
    const int kp   = idx % KPAD;
    const int rest = idx / KPAD;
    const int o    = rest % OC;
    const int d    = rest / OC;
    wpT[idx] = (kp < 132) ? wp[((size_t)d * 132 + kp) * OC + o] : 0.f;
}

// ---------------------------------------------------------------------------
// Kernel 1: S[n,m] = softmax_m(relu(E[n,:].E[m,:])) emitted as bf16.
__global__ __launch_bounds__(256) void supports_kernel(
    const float* __restrict__ E, unsigned short* __restrict__ S_hi)
{
    const int n   = blockIdx.x;
    const int tid = threadIdx.x;

    float en[D_EMB];
#pragma unroll
    for (int d = 0; d < D_EMB; ++d) en[d] = E[n * D_EMB + d];

    float vals[8];
    float mx = -1e30f;
#pragma unroll
    for (int j = 0; j < 8; ++j) {
        const int m = tid + j * 256;
        float dot = 0.f;
#pragma unroll
        for (int d = 0; d < D_EMB; ++d) dot += en[d] * E[m * D_EMB + d];
        dot = fmaxf(dot, 0.f);
        vals[j] = dot;
        mx = fmaxf(mx, dot);
    }

    __shared__ float sred[4];
    for (int off = 32; off > 0; off >>= 1) mx = fmaxf(mx, __shfl_xor(mx, off));
    if ((tid & 63) == 0) sred[tid >> 6] = mx;
    __syncthreads();
    mx = fmaxf(fmaxf(sred[0], sred[1]), fmaxf(sred[2], sred[3]));

    float sum = 0.f;
#pragma unroll
    for (int j = 0; j < 8; ++j) { vals[j] = __expf(vals[j] - mx); sum += vals[j]; }

    __syncthreads();
    for (int off = 32; off > 0; off >>= 1) sum += __shfl_xor(sum, off);
    if ((tid & 63) == 0) sred[tid >> 6] = sum;
    __syncthreads();
    sum = sred[0] + sred[1] + sred[2] + sred[3];

    const float inv = 1.f / sum;
#pragma unroll
    for (int j = 0; j < 8; ++j)
        S_hi[(size_t)n * N_NODES + tid + j * 256] = f2bf_rn(vals[j] * inv);
}

// ---------------------------------------------------------------------------
// Kernel 2: zero IN[:, :, 134..159] (ws is re-poisoned before every call).
__global__ __launch_bounds__(256) void zero_tail_kernel(unsigned short* __restrict__ IN)
{
    const int idx = blockIdx.x * 256 + threadIdx.x;   // rows * 13 dwords
    if (idx >= N_NODES * BATCH * 13) return;
    const int row = idx / 13, j = idx % 13;
    *(unsigned int*)((char*)IN + (size_t)row * INP * 2 + 268 + j * 4) = 0u;
}

// ---------------------------------------------------------------------------
// Kernel 3: build XT[col=b*CP+c][m] bf16 for the GEMM B operand.
// pass 0: channels from x/state(f32); pass 1: channels from x/IN-zs(bf16).
__global__ __launch_bounds__(256) void build_xt_kernel(
    const float* __restrict__ x, const float* __restrict__ state,
    const unsigned short* __restrict__ INz, const int use_zs,
    unsigned short* __restrict__ XT)
{
    const int b   = blockIdx.y;
    const int m0  = blockIdx.x * 64;
    const int tid = threadIdx.x;
    __shared__ float T[64][69];   // +1 pad: conflict-free column reads

    {
        const int r = tid >> 2;
        const int q = (tid & 3) * 16;
        if (use_zs) {
            const unsigned int* p = (const unsigned int*)
                ((const char*)INz + (((size_t)(m0 + r) * BATCH + b) * INP + 2 + q) * 2);
#pragma unroll
            for (int t = 0; t < 8; ++t) {
                const unsigned int v = p[t];
                T[r][DIN + q + 2 * t]     = bf2f((unsigned short)(v & 0xFFFFu));
                T[r][DIN + q + 2 * t + 1] = bf2f((unsigned short)(v >> 16));
            }
        } else {
#pragma unroll
            for (int u = 0; u < 4; ++u) {
                const float4 v = *(const float4*)&state[((size_t)b * N_NODES + m0 + r) * DOUT + q + u * 4];
                T[r][DIN + q + u * 4 + 0] = v.x;
                T[r][DIN + q + u * 4 + 1] = v.y;
                T[r][DIN + q + u * 4 + 2] = v.z;
                T[r][DIN + q + u * 4 + 3] = v.w;
            }
        }
    }
    if (tid < 128) {
        const int r = tid >> 1, c = tid & 1;
        T[r][c] = x[((size_t)b * N_NODES + m0 + r) * DIN + c];
        T[r][CIN + c] = 0.f;   // pad channels 66,67
    }
    __syncthreads();

    for (int idx = tid; idx < CP * 64; idx += 256) {
        const int c  = idx >> 6;
        const int mm = idx & 63;
        XT[((size_t)(b * CP + c)) * N_NODES + m0 + mm] = f2bf_rn(T[mm][c]);
    }
}

// ---------------------------------------------------------------------------
// Kernel 4: bf16 MFMA GEMM, 64x128 tile, 4 waves, double-buffered 2-phase.
// Grid 1088 = 32(bm) x 34(bn) = 8 XCDs x 136 (bijective remap).
// More independent blocks/CU (4.25) -> cross-block latency interleave.
// Epilogue writes bf16 into IN[n][b][66+c].
__global__ __launch_bounds__(256) void gemm_mfma_kernel(
    const unsigned short* __restrict__ A,
    const unsigned short* __restrict__ BT, unsigned short* __restrict__ INout)
{
    __shared__ __align__(16) unsigned short As[2][2048];  // 64 rows x 32 k
    __shared__ __align__(16) unsigned short Bs[2][4096];  // 128 rows x 32 k

    const int tid  = threadIdx.x;
    const int lane = tid & 63;
    const int w    = tid >> 6;             // 4 waves
    const int wr   = w >> 1, wc = w & 1;   // wave tile: 32 rows x 64 cols

    // bijective XCD remap: 1088 blocks = 8 * 136
    const int wg   = blockIdx.x;
    const int wgid = (wg & 7) * 136 + (wg >> 3);
    const int bn   = wgid % 34;
    const int bm   = wgid / 34;

    f32x4 acc[2][4];
#pragma unroll
    for (int i = 0; i < 2; ++i)
#pragma unroll
        for (int j = 0; j < 4; ++j) acc[i][j] = (f32x4){0.f, 0.f, 0.f, 0.f};

    // staging: LDS entry e (16B) holds row (e>>6)*16+(e&15), k-slice ((e>>4)&3)*8.
    // A: 256 entries (thread t -> entry t). B: 512 entries (t and t+256).
    const int srow = ((tid >> 6) << 4) + (tid & 15);
    const int scol = ((tid >> 4) & 3) * 8;
    const unsigned a_off  = (unsigned)(bm * 64 + srow) * MK + scol;
    const unsigned b_off0 = (unsigned)(bn * 128 + srow) * MK + scol;
    const unsigned b_off1 = b_off0 + 64u * MK;

    // prologue: stage tile 0 into buffer 0
    gload_lds16(A  + a_off,  &As[0][tid * 8]);
    gload_lds16(BT + b_off0, &Bs[0][tid * 8]);
    gload_lds16(BT + b_off1, &Bs[0][2048 + tid * 8]);

    int cur = 0;
#pragma unroll 1
    for (int k0 = 0; k0 < MK - 32; k0 += 32) {
        __syncthreads();   // implicit vmcnt(0): buf[cur] ready; buf[cur^1] free

        // issue next-tile stage (overlaps with ds_read + MFMA below)
        gload_lds16(A  + a_off  + k0 + 32, &As[cur ^ 1][tid * 8]);
        gload_lds16(BT + b_off0 + k0 + 32, &Bs[cur ^ 1][tid * 8]);
        gload_lds16(BT + b_off1 + k0 + 32, &Bs[cur ^ 1][2048 + tid * 8]);

        bf16x8 af[2], bf[4];
#pragma unroll
        for (int i = 0; i < 2; ++i)
            af[i] = *(const bf16x8*)(&As[cur][((wr * 2 + i) * 64 + lane) * 8]);
#pragma unroll
        for (int j = 0; j < 4; ++j)
            bf[j] = *(const bf16x8*)(&Bs[cur][((wc * 4 + j) * 64 + lane) * 8]);
#pragma unroll
        for (int i = 0; i < 2; ++i)
#pragma unroll
            for (int j = 0; j < 4; ++j)
                acc[i][j] = __builtin_amdgcn_mfma_f32_16x16x32_bf16(
                    af[i], bf[j], acc[i][j], 0, 0, 0);
        cur ^= 1;
    }
    __syncthreads();   // last tile visible

    {
        bf16x8 af[2], bf[4];
#pragma unroll
        for (int i = 0; i < 2; ++i)
            af[i] = *(const bf16x8*)(&As[cur][((wr * 2 + i) * 64 + lane) * 8]);
#pragma unroll
        for (int j = 0; j < 4; ++j)
            bf[j] = *(const bf16x8*)(&Bs[cur][((wc * 4 + j) * 64 + lane) * 8]);
#pragma unroll
        for (int i = 0; i < 2; ++i)
#pragma unroll
            for (int j = 0; j < 4; ++j)
                acc[i][j] = __builtin_amdgcn_mfma_f32_16x16x32_bf16(
                    af[i], bf[j], acc[i][j], 0, 0, 0);
    }

    const int crow0 = bm * 64 + wr * 32;
    const int ccol0 = bn * 128 + wc * 64;
#pragma unroll
    for (int j = 0; j < 4; ++j) {
        const int col = ccol0 + j * 16 + (lane & 15);
        const int b   = col / 68;
        const int c   = col - b * 68;
#pragma unroll
        for (int i = 0; i < 2; ++i)
#pragma unroll
            for (int r = 0; r < 4; ++r) {
                const int row = crow0 + i * 16 + (lane >> 4) * 4 + r;   // = n
                INout[((size_t)row * BATCH + b) * INP + 66 + c] = f2bf_rn(acc[i][j][r]);
            }
    }
}

// ---------------------------------------------------------------------------
// Kernel 5: weight precompute. Writes per-node blobs in fragment order:
// blob(node) = [half NH][hi 20KB][lo 20KB]; addr = frag_addr (pre-swizzled).
// grid: (NH*1280/256, nN/16); thread = one (half,o,s) column x 16 nodes.
__global__ __launch_bounds__(256) void wgen_kernel(
    const float* __restrict__ E, const float* __restrict__ wpT,
    unsigned char* __restrict__ Wc, int n0, int NH, int OC)
{
    const int tid  = threadIdx.x;
    const int cid  = blockIdx.x * 256 + tid;   // exact: NH*1280 total
    const int half = cid / 1280;
    const int rest = cid % 1280;
    const int o_l  = rest / 20;
    const int s    = rest % 20;
    const int o_g  = half * 64 + o_l;

    __shared__ float en_s[16][D_EMB];
    if (tid < 16 * D_EMB) {
        const int i = tid / D_EMB, d = tid % D_EMB;
        en_s[i][d] = E[(n0 + blockIdx.y * 16 + i) * D_EMB + d];
    }

    float wv[D_EMB][8];
    if (s < 17) {
        const float* p = wpT + (size_t)o_g * KPAD + s * 8;
#pragma unroll
        for (int d = 0; d < D_EMB; ++d) {
            const float4 a = *(const float4*)(p + (size_t)d * OC * KPAD);
            const float4 b = *(const float4*)(p + (size_t)d * OC * KPAD + 4);
            wv[d][0] = a.x; wv[d][1] = a.y; wv[d][2] = a.z; wv[d][3] = a.w;
            wv[d][4] = b.x; wv[d][5] = b.y; wv[d][6] = b.z; wv[d][7] = b.w;
        }
    } else {
#pragma unroll
        for (int d = 0; d < D_EMB; ++d)
#pragma unroll
            for (int u = 0; u < 8; ++u) wv[d][u] = 0.f;
    }
    __syncthreads();

    const int addr = frag_addr(o_l >> 4, s >> 2, o_l & 15, s & 3);
    unsigned char* base0 = Wc + (size_t)blockIdx.y * 16 * NH * WBLOB + (size_t)half * WBLOB;
#pragma unroll 1
    for (int i = 0; i < 16; ++i) {
        float v[8] = {0.f, 0.f, 0.f, 0.f, 0.f, 0.f, 0.f, 0.f};
#pragma unroll
        for (int d = 0; d < D_EMB; ++d) {
            const float e = en_s[i][d];
#pragma unroll
            for (int u = 0; u < 8; ++u) v[u] += e * wv[d][u];
        }
        u16x8 hv, lv;
#pragma unroll
        for (int u = 0; u < 8; ++u) {
            const unsigned short h = f2bf_rn(v[u]);
            hv[u] = h;
            lv[u] = f2bf_rn(v[u] - bf2f(h));
        }
        unsigned char* nb = base0 + (size_t)i * NH * WBLOB;
        *(u16x8*)(nb + addr)         = hv;
        *(u16x8*)(nb + WHALF + addr) = lv;
    }
}

// ---------------------------------------------------------------------------
// A-fragment helpers (register-direct, no LDS)
union afrag { u16x8 u; bf16x8 s; };

// ---------------------------------------------------------------------------
// Kernel 6: gate transform. Grid (nN, 2). Stages 40 KB W blob linearly via
// global_load_lds; A-frags direct from x/state(f32) + IN-AG(bf16).
// half0 -> zs=bf16(sigmoid*state) into IN[2..65]; half1 -> r into Rb (bf16).
__global__ __launch_bounds__(256) void gate_mfma_kernel(
    const float* __restrict__ E, const float* __restrict__ bp,
    const float* __restrict__ x, const float* __restrict__ state,
    unsigned short* __restrict__ IN, const unsigned char* __restrict__ Wc,
    int n0, unsigned short* __restrict__ Rb)
{
    const int n_l  = blockIdx.x;
    const int n    = n0 + n_l;
    const int half = blockIdx.y;
    const int tid  = threadIdx.x;

    __shared__ __align__(16) unsigned char Ws[WBLOB];
    __shared__ float bias_l[64];

    const unsigned char* src = Wc + (size_t)n_l * (2 * WBLOB) + (size_t)half * WBLOB;
#pragma unroll
    for (int i = 0; i < 10; ++i)
        gload_lds16(src + (tid + i * 256) * 16, Ws + (tid + i * 256) * 16);

    if (tid < 64) {
        float s = 0.f;
#pragma unroll
        for (int d = 0; d < D_EMB; ++d)
            s += E[n * D_EMB + d] * bp[d * GOUT + half * 64 + tid];
        bias_l[tid] = s;
    }

    const int lane = tid & 63, w = tid >> 6;
    const int row = lane & 15, sl = lane >> 4;
    const int b = w * 16 + row;
    const float* stp = state + ((size_t)b * N_NODES + n) * DOUT;
    const float2 xv  = *(const float2*)(x + ((size_t)b * N_NODES + n) * DIN);
    const unsigned short* inr = IN + ((size_t)n * BATCH + b) * INP;

    afrag af[5];
    {   // kt0: k 0..31 -> x + state c0..29
        float f[8];
        if (sl == 0) {
            f[0] = xv.x; f[1] = xv.y;
            const float2 s0 = *(const float2*)(stp + 0);
            const float2 s1 = *(const float2*)(stp + 2);
            const float2 s2 = *(const float2*)(stp + 4);
            f[2] = s0.x; f[3] = s0.y; f[4] = s1.x; f[5] = s1.y; f[6] = s2.x; f[7] = s2.y;
        } else {
            const float* sp = stp + sl * 8 - 2;
#pragma unroll
            for (int t = 0; t < 4; ++t) {
                const float2 v = *(const float2*)(sp + 2 * t);
                f[2 * t] = v.x; f[2 * t + 1] = v.y;
            }
        }
#pragma unroll
        for (int u = 0; u < 8; ++u) af[0].u[u] = f2bf_rn(f[u]);
    }
    {   // kt1: k 32..63 -> state c30..61
        const float* sp = stp + 30 + sl * 8;
        float f[8];
#pragma unroll
        for (int t = 0; t < 4; ++t) {
            const float2 v = *(const float2*)(sp + 2 * t);
            f[2 * t] = v.x; f[2 * t + 1] = v.y;
        }
#pragma unroll
        for (int u = 0; u < 8; ++u) af[1].u[u] = f2bf_rn(f[u]);
    }
    if (sl == 0) {   // kt2 sl0: state c62,63 + IN k66..71
        af[2].u[0] = f2bf_rn(stp[62]);
        af[2].u[1] = f2bf_rn(stp[63]);
        const unsigned int* q = (const unsigned int*)((const char*)inr + 132);
        const unsigned int q0 = q[0], q1 = q[1], q2 = q[2];
        af[2].u[2] = (unsigned short)q0; af[2].u[3] = (unsigned short)(q0 >> 16);
        af[2].u[4] = (unsigned short)q1; af[2].u[5] = (unsigned short)(q1 >> 16);
        af[2].u[6] = (unsigned short)q2; af[2].u[7] = (unsigned short)(q2 >> 16);
    } else {
        af[2].u = *(const u16x8*)(inr + 64 + sl * 8);
    }
    af[3].u = *(const u16x8*)(inr + 96 + sl * 8);
    af[4].u = *(const u16x8*)(inr + 128 + sl * 8);

    __syncthreads();   // W blob + bias visible

    f32x4 acc[4];
#pragma unroll
    for (int j = 0; j < 4; ++j) acc[j] = (f32x4){0.f, 0.f, 0.f, 0.f};
#pragma unroll
    for (int j = 0; j < 4; ++j) {
#pragma unroll
        for (int kt = 0; kt < 5; ++kt) {
            const bf16x8 bh = *(const bf16x8*)(Ws + frag_addr(j, kt, row, sl));
            acc[j] = __builtin_amdgcn_mfma_f32_16x16x32_bf16(af[kt].s, bh, acc[j], 0, 0, 0);
        }
#pragma unroll
        for (int kt = 0; kt < 5; ++kt) {
            const bf16x8 bl = *(const bf16x8*)(Ws + WHALF + frag_addr(j, kt, row, sl));
            acc[j] = __builtin_amdgcn_mfma_f32_16x16x32_bf16(af[kt].s, bl, acc[j], 0, 0, 0);
        }
    }

#pragma unroll
    for (int j = 0; j < 4; ++j) {
        const int o_l = j * 16 + row;
        const float bs = bias_l[o_l];
#pragma unroll
        for (int r = 0; r < 4; ++r) {
            const int bb = w * 16 + sl * 4 + r;
            const float sg = 1.f / (1.f + __expf(-(acc[j][r] + bs)));
            if (half == 0) {
                const float st = state[((size_t)bb * N_NODES + n) * DOUT + o_l];
                IN[((size_t)n * BATCH + bb) * INP + 2 + o_l] = f2bf_rn(sg * st);
            } else {
                Rb[((size_t)n * BATCH + bb) * DOUT + o_l] = f2bf_rn(sg);
            }
        }
    }
}

// ---------------------------------------------------------------------------
// Kernel 7: update transform + GRU output. Grid nN.
__global__ __launch_bounds__(256) void update_mfma_kernel(
    const float* __restrict__ E, const float* __restrict__ bp,
    const float* __restrict__ x, const float* __restrict__ state,
    const unsigned short* __restrict__ IN, const unsigned char* __restrict__ Wc,
    int n0, const unsigned short* __restrict__ Rb, float* __restrict__ out)
{
    const int n_l = blockIdx.x;
    const int n   = n0 + n_l;
    const int tid = threadIdx.x;

    __shared__ __align__(16) unsigned char Ws[WBLOB];
    __shared__ float bias_l[64];

    const unsigned char* src = Wc + (size_t)n_l * WBLOB;
#pragma unroll
    for (int i = 0; i < 10; ++i)
        gload_lds16(src + (tid + i * 256) * 16, Ws + (tid + i * 256) * 16);

    if (tid < 64) {
        float s = 0.f;
#pragma unroll
        for (int d = 0; d < D_EMB; ++d)
            s += E[n * D_EMB + d] * bp[d * DOUT + tid];
        bias_l[tid] = s;
    }

    const int lane = tid & 63, w = tid >> 6;
    const int row = lane & 15, sl = lane >> 4;
    const int b = w * 16 + row;
    const unsigned short* inr = IN + ((size_t)n * BATCH + b) * INP;

    afrag af[5];
    if (sl == 0) {   // kt0 sl0: x + zs k2..7
        const float2 xv = *(const float2*)(x + ((size_t)b * N_NODES + n) * DIN);
        af[0].u[0] = f2bf_rn(xv.x);
        af[0].u[1] = f2bf_rn(xv.y);
        const unsigned int* q = (const unsigned int*)((const char*)inr + 4);
        const unsigned int q0 = q[0], q1 = q[1], q2 = q[2];
        af[0].u[2] = (unsigned short)q0; af[0].u[3] = (unsigned short)(q0 >> 16);
        af[0].u[4] = (unsigned short)q1; af[0].u[5] = (unsigned short)(q1 >> 16);
        af[0].u[6] = (unsigned short)q2; af[0].u[7] = (unsigned short)(q2 >> 16);
    } else {
        af[0].u = *(const u16x8*)(inr + sl * 8);
    }
#pragma unroll
    for (int kt = 1; kt < 5; ++kt)
        af[kt].u = *(const u16x8*)(inr + kt * 32 + sl * 8);

    __syncthreads();

    f32x4 acc[4];
#pragma unroll
    for (int j = 0; j < 4; ++j) acc[j] = (f32x4){0.f, 0.f, 0.f, 0.f};
#pragma unroll
    for (int j = 0; j < 4; ++j) {
#pragma unroll
        for (int kt = 0; kt < 5; ++kt) {
            const bf16x8 bh = *(const bf16x8*)(Ws + frag_addr(j, kt, row, sl));
            acc[j] = __builtin_amdgcn_mfma_f32_16x16x32_bf16(af[kt].s, bh, acc[j], 0, 0, 0);
        }
#pragma unroll
        for (int kt = 0; kt < 5; ++kt) {
            const bf16x8 bl = *(const bf16x8*)(Ws + WHALF + frag_addr(j, kt, row, sl));
            acc[j] = __builtin_amdgcn_mfma_f32_16x16x32_bf16(af[kt].s, bl, acc[j], 0, 0, 0);
        }
    }

#pragma unroll
    for (int j = 0; j < 4; ++j) {
        const int o_l = j * 16 + row;
        const float bs = bias_l[o_l];
#pragma unroll
        for (int r = 0; r < 4; ++r) {
            const int bb = w * 16 + sl * 4 + r;
            const float hc = tanhf(acc[j][r] + bs);
            const float rr = bf2f(Rb[((size_t)n * BATCH + bb) * DOUT + o_l]);
            const float st = state[((size_t)bb * N_NODES + n) * DOUT + o_l];
            out[((size_t)bb * N_NODES + n) * DOUT + o_l] = rr * st + (1.f - rr) * hc;
        }
    }
}

// ---------------------------------------------------------------------------
extern "C" void kernel_launch(void* const* d_in, const int* in_sizes, int n_in,
                              void* d_out, int out_size, void* d_ws, size_t ws_size,
                              hipStream_t stream)
{
    const float* x  = (const float*)d_in[0];
    const float* st = (const float*)d_in[1];
    const float* E  = (const float*)d_in[2];
    const float* gw = (const float*)d_in[3];
    const float* gb = (const float*)d_in[4];
    const float* uw = (const float*)d_in[5];
    const float* ub = (const float*)d_in[6];
    float* out = (float*)d_out;

    // fixed workspace layout (85.98 MB) + adaptive weight-chunk buffer
    unsigned char* ws = (unsigned char*)d_ws;
    unsigned short* S_hi = (unsigned short*)ws;                       // 8,388,608
    unsigned short* XT   = (unsigned short*)(ws + 8388608);           // 17,825,792
    unsigned short* IN   = (unsigned short*)(ws + 26214400);          // 41,943,040
    unsigned short* Rb   = (unsigned short*)(ws + 68157440);          // 16,777,216
    float* wpTg          = (float*)(ws + 84934656);                   //    696,320
    float* wpTu          = (float*)(ws + 85630976);                   //    348,160
    unsigned char* Wc    = ws + 85979136;

    // chunk size: largest power-of-two node count whose gate blobs fit
    const size_t fixed_b = 85979136;
    int C = 64;
    const int cands[5] = {2048, 1024, 512, 256, 128};
    for (int i = 0; i < 5; ++i) {
        if (ws_size >= fixed_b + (size_t)cands[i] * (2 * WBLOB)) { C = cands[i]; break; }
    }
    const int nch = N_NODES / C;

    const int tg = D_EMB * GOUT * KPAD;
    const int tu = D_EMB * DOUT * KPAD;
    transpose_pool_kernel<<<(tg + 255) / 256, 256, 0, stream>>>(gw, wpTg, GOUT, tg);
    transpose_pool_kernel<<<(tu + 255) / 256, 256, 0, stream>>>(uw, wpTu, DOUT, tu);

    supports_kernel<<<N_NODES, 256, 0, stream>>>(E, S_hi);
    zero_tail_kernel<<<(N_NODES * BATCH * 13 + 255) / 256, 256, 0, stream>>>(IN);
    build_xt_kernel<<<dim3(N_NODES / 64, BATCH), 256, 0, stream>>>(x, st, IN, 0, XT);
    gemm_mfma_kernel<<<1088, 256, 0, stream>>>(S_hi, XT, IN);

    for (int ch = 0; ch < nch; ++ch) {
        const int n0 = ch * C;
        wgen_kernel<<<dim3(10, C / 16), 256, 0, stream>>>(E, wpTg, Wc, n0, 2, GOUT);
        gate_mfma_kernel<<<dim3(C, 2), 256, 0, stream>>>(E, gb, x, st, IN, Wc, n0, Rb);
    }

    build_xt_kernel<<<dim3(N_NODES / 64, BATCH), 256, 0, stream>>>(x, st, IN, 1, XT);
    gemm_mfma_kernel<<<1088, 256, 0, stream>>>(S_hi, XT, IN);

    for (int ch = 0; ch < nch; ++ch) {
        const int n0 = ch * C;
        wgen_kernel<<<dim3(5, C / 16), 256, 0, stream>>>(E, wpTu, Wc, n0, 1, DOUT);
        update_mfma_kernel<<<C, 256, 0, stream>>>(E, ub, x, st, IN, Wc, n0, Rb, out);
    }
}

// Round 9
// 488.726 us; speedup vs baseline: 1.1247x; 1.1247x over previous
//
#include <hip/hip_runtime.h>
#include <math.h>

#define N_NODES 2048
#define BATCH   64
#define DIN     2
#define DOUT    64
#define CIN     66     // DIN + DOUT
#define CP      68     // padded channel count (GEMM col blocking)
#define D_EMB   10
#define GOUT    128    // gate output channels (2*DOUT)
#define NCOLS   (BATCH*CP)   // 4352, GEMM N dimension
#define MK      2048         // GEMM K
#define NT      (MK/32)      // 64 K-tiles
#define KPAD    136          // wpT row pitch
#define INP     160          // IN row pitch (bf16 elems): [0,1]=unused [2,65]=zs [66,133]=AG [134,159]=0
#define WHALF   20480        // bytes per hi (or lo) fragment half-blob (64o x 160k bf16)
#define WBLOB   40960        // hi+lo per (node, o-half)

typedef __attribute__((ext_vector_type(8))) short bf16x8;
typedef __attribute__((ext_vector_type(8))) unsigned short u16x8;
typedef __attribute__((ext_vector_type(4))) float f32x4;

__device__ __forceinline__ unsigned short f2bf_rn(float f) {
    unsigned u = __builtin_bit_cast(unsigned, f);
    unsigned r = u + 0x7FFFu + ((u >> 16) & 1u);   // RNE
    return (unsigned short)(r >> 16);
}
__device__ __forceinline__ float bf2f(unsigned short h) {
    unsigned u = ((unsigned)h) << 16;
    return __builtin_bit_cast(float, u);
}

__device__ __forceinline__ void gload_lds16(const void* g, void* l) {
    __builtin_amdgcn_global_load_lds(
        (const __attribute__((address_space(1))) unsigned int*)g,
        (__attribute__((address_space(3))) unsigned int*)l, 16, 0, 0);
}

// Fragment-layout address inside a 20 KB half-blob: [strip4][kt5][row16][sl4]x16B,
// XOR swizzle spreads the 64B rows across banks (uniform 2-way on b128 reads).
__device__ __forceinline__ int frag_addr(int strip, int kt, int row, int slice) {
    const int byte = ((strip * 5 + kt) * 16 + row) * 64 + slice * 16;
    return byte ^ ((row & 7) << 4);
}

// ---------------------------------------------------------------------------
// Kernel 0: wpT[d][o][kp] = wp[d][kp][o], kp padded to 136 with zeros.
__global__ __launch_bounds__(256) void transpose_pool_kernel(
    const float* __restrict__ wp, float* __restrict__ wpT, int OC, int total)
{
    const int idx = blockIdx.x * 256 + threadIdx.x;
    if (idx >= total) return;
    const int kp   = idx % KPAD;
    const int rest = idx / KPAD;
    const int o    = rest % OC;
    const int d    = rest / OC;
    wpT[idx] = (kp < 132) ? wp[((size_t)d * 132 + kp) * OC + o] : 0.f;
}

// ---------------------------------------------------------------------------
// Kernel 1: S[n,m] = softmax_m(relu(E[n,:].E[m,:])) emitted as bf16.
__global__ __launch_bounds__(256) void supports_kernel(
    const float* __restrict__ E, unsigned short* __restrict__ S_hi)
{
    const int n   = blockIdx.x;
    const int tid = threadIdx.x;

    float en[D_EMB];
#pragma unroll
    for (int d = 0; d < D_EMB; ++d) en[d] = E[n * D_EMB + d];

    float vals[8];
    float mx = -1e30f;
#pragma unroll
    for (int j = 0; j < 8; ++j) {
        const int m = tid + j * 256;
        float dot = 0.f;
#pragma unroll
        for (int d = 0; d < D_EMB; ++d) dot += en[d] * E[m * D_EMB + d];
        dot = fmaxf(dot, 0.f);
        vals[j] = dot;
        mx = fmaxf(mx, dot);
    }

    __shared__ float sred[4];
    for (int off = 32; off > 0; off >>= 1) mx = fmaxf(mx, __shfl_xor(mx, off));
    if ((tid & 63) == 0) sred[tid >> 6] = mx;
    __syncthreads();
    mx = fmaxf(fmaxf(sred[0], sred[1]), fmaxf(sred[2], sred[3]));

    float sum = 0.f;
#pragma unroll
    for (int j = 0; j < 8; ++j) { vals[j] = __expf(vals[j] - mx); sum += vals[j]; }

    __syncthreads();
    for (int off = 32; off > 0; off >>= 1) sum += __shfl_xor(sum, off);
    if ((tid & 63) == 0) sred[tid >> 6] = sum;
    __syncthreads();
    sum = sred[0] + sred[1] + sred[2] + sred[3];

    const float inv = 1.f / sum;
#pragma unroll
    for (int j = 0; j < 8; ++j)
        S_hi[(size_t)n * N_NODES + tid + j * 256] = f2bf_rn(vals[j] * inv);
}

// ---------------------------------------------------------------------------
// Kernel 2: zero IN[:, :, 134..159] (ws is re-poisoned before every call).
__global__ __launch_bounds__(256) void zero_tail_kernel(unsigned short* __restrict__ IN)
{
    const int idx = blockIdx.x * 256 + threadIdx.x;   // rows * 13 dwords
    if (idx >= N_NODES * BATCH * 13) return;
    const int row = idx / 13, j = idx % 13;
    *(unsigned int*)((char*)IN + (size_t)row * INP * 2 + 268 + j * 4) = 0u;
}

// ---------------------------------------------------------------------------
// Kernel 3: build XT[col=b*CP+c][m] bf16 for the GEMM B operand.
// pass 0: channels from x/state(f32); pass 1: channels from x/IN-zs(bf16).
__global__ __launch_bounds__(256) void build_xt_kernel(
    const float* __restrict__ x, const float* __restrict__ state,
    const unsigned short* __restrict__ INz, const int use_zs,
    unsigned short* __restrict__ XT)
{
    const int b   = blockIdx.y;
    const int m0  = blockIdx.x * 64;
    const int tid = threadIdx.x;
    __shared__ float T[64][69];   // +1 pad: conflict-free column reads

    {
        const int r = tid >> 2;
        const int q = (tid & 3) * 16;
        if (use_zs) {
            const unsigned int* p = (const unsigned int*)
                ((const char*)INz + (((size_t)(m0 + r) * BATCH + b) * INP + 2 + q) * 2);
#pragma unroll
            for (int t = 0; t < 8; ++t) {
                const unsigned int v = p[t];
                T[r][DIN + q + 2 * t]     = bf2f((unsigned short)(v & 0xFFFFu));
                T[r][DIN + q + 2 * t + 1] = bf2f((unsigned short)(v >> 16));
            }
        } else {
#pragma unroll
            for (int u = 0; u < 4; ++u) {
                const float4 v = *(const float4*)&state[((size_t)b * N_NODES + m0 + r) * DOUT + q + u * 4];
                T[r][DIN + q + u * 4 + 0] = v.x;
                T[r][DIN + q + u * 4 + 1] = v.y;
                T[r][DIN + q + u * 4 + 2] = v.z;
                T[r][DIN + q + u * 4 + 3] = v.w;
            }
        }
    }
    if (tid < 128) {
        const int r = tid >> 1, c = tid & 1;
        T[r][c] = x[((size_t)b * N_NODES + m0 + r) * DIN + c];
        T[r][CIN + c] = 0.f;   // pad channels 66,67
    }
    __syncthreads();

    for (int idx = tid; idx < CP * 64; idx += 256) {
        const int c  = idx >> 6;
        const int mm = idx & 63;
        XT[((size_t)(b * CP + c)) * N_NODES + m0 + mm] = f2bf_rn(T[mm][c]);
    }
}

// ---------------------------------------------------------------------------
// Kernel 4: bf16 MFMA GEMM, 128x128 tile, 4 waves, 3-buffer depth-2 pipeline
// with COUNTED vmcnt (T4): per K-step {vmcnt(4); s_barrier; STAGE(i+2);
// ds_read cur; MFMA}. No vmcnt(0) drain in the main loop.
// Grid 544 = 8 XCDs x 68 (bijective remap). Epilogue -> bf16 IN[n][b][66+c].
__global__ __launch_bounds__(256) void gemm_mfma_kernel(
    const unsigned short* __restrict__ A,
    const unsigned short* __restrict__ BT, unsigned short* __restrict__ INout)
{
    __shared__ __align__(16) unsigned short As[3][4096];  // 3 x 8 KB
    __shared__ __align__(16) unsigned short Bs[3][4096];

    const int tid  = threadIdx.x;
    const int lane = tid & 63;
    const int w    = tid >> 6;             // 4 waves
    const int wr   = w >> 1, wc = w & 1;   // wave tile: 64 x 64

    // bijective XCD remap: 544 blocks = 8 * 68
    const int wg   = blockIdx.x;
    const int wgid = (wg & 7) * 68 + (wg >> 3);
    const int bn   = wgid % 34;
    const int bm   = wgid / 34;

    f32x4 acc[4][4];
#pragma unroll
    for (int i = 0; i < 4; ++i)
#pragma unroll
        for (int j = 0; j < 4; ++j) acc[i][j] = (f32x4){0.f, 0.f, 0.f, 0.f};

    // staging: LDS entry e (16B) holds row (e>>6)*16+(e&15), k-slice ((e>>4)&3)*8.
    // 512 entries per tile; thread t stages entries t and t+256 (4 loads/iter).
    const int srow = ((tid >> 6) << 4) + (tid & 15);
    const int scol = ((tid >> 4) & 3) * 8;
    const unsigned a_off0 = (unsigned)(bm * 128 + srow) * MK + scol;
    const unsigned a_off1 = a_off0 + 64u * MK;
    const unsigned b_off0 = (unsigned)(bn * 128 + srow) * MK + scol;
    const unsigned b_off1 = b_off0 + 64u * MK;

#define STAGE(k0, bs)                                              \
    do {                                                           \
        gload_lds16(A  + a_off0 + (k0), &As[bs][tid * 8]);         \
        gload_lds16(A  + a_off1 + (k0), &As[bs][2048 + tid * 8]);  \
        gload_lds16(BT + b_off0 + (k0), &Bs[bs][tid * 8]);         \
        gload_lds16(BT + b_off1 + (k0), &Bs[bs][2048 + tid * 8]);  \
    } while (0)

    // prologue: depth-2 prefetch (8 loads outstanding)
    STAGE(0, 0);
    STAGE(32, 1);

    int cur = 0;
#pragma unroll 1
    for (int i = 0; i < NT; ++i) {
        // per-wave: own oldest 4 loads (tile i) complete; barrier makes global
        if (i < NT - 1) asm volatile("s_waitcnt vmcnt(4)" ::: "memory");
        else            asm volatile("s_waitcnt vmcnt(0)" ::: "memory");
        __builtin_amdgcn_s_barrier();   // raw: no vmcnt(0) drain

        if (i + 2 < NT) {
            const int nb = (cur + 2 >= 3) ? cur - 1 : cur + 2;
            STAGE((i + 2) * 32, nb);
        }

        bf16x8 af[4], bf[4];
#pragma unroll
        for (int q = 0; q < 4; ++q)
            af[q] = *(const bf16x8*)(&As[cur][((wr * 4 + q) * 64 + lane) * 8]);
#pragma unroll
        for (int j = 0; j < 4; ++j)
            bf[j] = *(const bf16x8*)(&Bs[cur][((wc * 4 + j) * 64 + lane) * 8]);
#pragma unroll
        for (int q = 0; q < 4; ++q)
#pragma unroll
            for (int j = 0; j < 4; ++j)
                acc[q][j] = __builtin_amdgcn_mfma_f32_16x16x32_bf16(
                    af[q], bf[j], acc[q][j], 0, 0, 0);

        cur = (cur + 1 >= 3) ? 0 : cur + 1;
    }
#undef STAGE

    const int crow0 = bm * 128 + wr * 64;
    const int ccol0 = bn * 128 + wc * 64;
#pragma unroll
    for (int j = 0; j < 4; ++j) {
        const int col = ccol0 + j * 16 + (lane & 15);
        const int b   = col / 68;
        const int c   = col - b * 68;
#pragma unroll
        for (int q = 0; q < 4; ++q)
#pragma unroll
            for (int r = 0; r < 4; ++r) {
                const int row = crow0 + q * 16 + (lane >> 4) * 4 + r;   // = n
                INout[((size_t)row * BATCH + b) * INP + 66 + c] = f2bf_rn(acc[q][j][r]);
            }
    }
}

// ---------------------------------------------------------------------------
// Kernel 5: weight precompute. Writes per-node blobs in fragment order:
// blob(node) = [half NH][hi 20KB][lo 20KB]; addr = frag_addr (pre-swizzled).
// grid: (NH*1280/256, nN/16); thread = one (half,o,s) column x 16 nodes.
__global__ __launch_bounds__(256) void wgen_kernel(
    const float* __restrict__ E, const float* __restrict__ wpT,
    unsigned char* __restrict__ Wc, int n0, int NH, int OC)
{
    const int tid  = threadIdx.x;
    const int cid  = blockIdx.x * 256 + tid;   // exact: NH*1280 total
    const int half = cid / 1280;
    const int rest = cid % 1280;
    const int o_l  = rest / 20;
    const int s    = rest % 20;
    const int o_g  = half * 64 + o_l;

    __shared__ float en_s[16][D_EMB];
    if (tid < 16 * D_EMB) {
        const int i = tid / D_EMB, d = tid % D_EMB;
        en_s[i][d] = E[(n0 + blockIdx.y * 16 + i) * D_EMB + d];
    }

    float wv[D_EMB][8];
    if (s < 17) {
        const float* p = wpT + (size_t)o_g * KPAD + s * 8;
#pragma unroll
        for (int d = 0; d < D_EMB; ++d) {
            const float4 a = *(const float4*)(p + (size_t)d * OC * KPAD);
            const float4 b = *(const float4*)(p + (size_t)d * OC * KPAD + 4);
            wv[d][0] = a.x; wv[d][1] = a.y; wv[d][2] = a.z; wv[d][3] = a.w;
            wv[d][4] = b.x; wv[d][5] = b.y; wv[d][6] = b.z; wv[d][7] = b.w;
        }
    } else {
#pragma unroll
        for (int d = 0; d < D_EMB; ++d)
#pragma unroll
            for (int u = 0; u < 8; ++u) wv[d][u] = 0.f;
    }
    __syncthreads();

    const int addr = frag_addr(o_l >> 4, s >> 2, o_l & 15, s & 3);
    unsigned char* base0 = Wc + (size_t)blockIdx.y * 16 * NH * WBLOB + (size_t)half * WBLOB;
#pragma unroll 1
    for (int i = 0; i < 16; ++i) {
        float v[8] = {0.f, 0.f, 0.f, 0.f, 0.f, 0.f, 0.f, 0.f};
#pragma unroll
        for (int d = 0; d < D_EMB; ++d) {
            const float e = en_s[i][d];
#pragma unroll
            for (int u = 0; u < 8; ++u) v[u] += e * wv[d][u];
        }
        u16x8 hv, lv;
#pragma unroll
        for (int u = 0; u < 8; ++u) {
            const unsigned short h = f2bf_rn(v[u]);
            hv[u] = h;
            lv[u] = f2bf_rn(v[u] - bf2f(h));
        }
        unsigned char* nb = base0 + (size_t)i * NH * WBLOB;
        *(u16x8*)(nb + addr)         = hv;
        *(u16x8*)(nb + WHALF + addr) = lv;
    }
}

// ---------------------------------------------------------------------------
// A-fragment helpers (register-direct, no LDS)
union afrag { u16x8 u; bf16x8 s; };

// ---------------------------------------------------------------------------
// Kernel 6: gate transform. Grid (nN, 2). Stages 40 KB W blob linearly via
// global_load_lds; A-frags direct from x/state(f32) + IN-AG(bf16).
// half0 -> zs=bf16(sigmoid*state) into IN[2..65]; half1 -> r into Rb (bf16).
__global__ __launch_bounds__(256) void gate_mfma_kernel(
    const float* __restrict__ E, const float* __restrict__ bp,
    const float* __restrict__ x, const float* __restrict__ state,
    unsigned short* __restrict__ IN, const unsigned char* __restrict__ Wc,
    int n0, unsigned short* __restrict__ Rb)
{
    const int n_l  = blockIdx.x;
    const int n    = n0 + n_l;
    const int half = blockIdx.y;
    const int tid  = threadIdx.x;

    __shared__ __align__(16) unsigned char Ws[WBLOB];
    __shared__ float bias_l[64];

    const unsigned char* src = Wc + (size_t)n_l * (2 * WBLOB) + (size_t)half * WBLOB;
#pragma unroll
    for (int i = 0; i < 10; ++i)
        gload_lds16(src + (tid + i * 256) * 16, Ws + (tid + i * 256) * 16);

    if (tid < 64) {
        float s = 0.f;
#pragma unroll
        for (int d = 0; d < D_EMB; ++d)
            s += E[n * D_EMB + d] * bp[d * GOUT + half * 64 + tid];
        bias_l[tid] = s;
    }

    const int lane = tid & 63, w = tid >> 6;
    const int row = lane & 15, sl = lane >> 4;
    const int b = w * 16 + row;
    const float* stp = state + ((size_t)b * N_NODES + n) * DOUT;
    const float2 xv  = *(const float2*)(x + ((size_t)b * N_NODES + n) * DIN);
    const unsigned short* inr = IN + ((size_t)n * BATCH + b) * INP;

    afrag af[5];
    {   // kt0: k 0..31 -> x + state c0..29
        float f[8];
        if (sl == 0) {
            f[0] = xv.x; f[1] = xv.y;
            const float2 s0 = *(const float2*)(stp + 0);
            const float2 s1 = *(const float2*)(stp + 2);
            const float2 s2 = *(const float2*)(stp + 4);
            f[2] = s0.x; f[3] = s0.y; f[4] = s1.x; f[5] = s1.y; f[6] = s2.x; f[7] = s2.y;
        } else {
            const float* sp = stp + sl * 8 - 2;
#pragma unroll
            for (int t = 0; t < 4; ++t) {
                const float2 v = *(const float2*)(sp + 2 * t);
                f[2 * t] = v.x; f[2 * t + 1] = v.y;
            }
        }
#pragma unroll
        for (int u = 0; u < 8; ++u) af[0].u[u] = f2bf_rn(f[u]);
    }
    {   // kt1: k 32..63 -> state c30..61
        const float* sp = stp + 30 + sl * 8;
        float f[8];
#pragma unroll
        for (int t = 0; t < 4; ++t) {
            const float2 v = *(const float2*)(sp + 2 * t);
            f[2 * t] = v.x; f[2 * t + 1] = v.y;
        }
#pragma unroll
        for (int u = 0; u < 8; ++u) af[1].u[u] = f2bf_rn(f[u]);
    }
    if (sl == 0) {   // kt2 sl0: state c62,63 + IN k66..71
        af[2].u[0] = f2bf_rn(stp[62]);
        af[2].u[1] = f2bf_rn(stp[63]);
        const unsigned int* q = (const unsigned int*)((const char*)inr + 132);
        const unsigned int q0 = q[0], q1 = q[1], q2 = q[2];
        af[2].u[2] = (unsigned short)q0; af[2].u[3] = (unsigned short)(q0 >> 16);
        af[2].u[4] = (unsigned short)q1; af[2].u[5] = (unsigned short)(q1 >> 16);
        af[2].u[6] = (unsigned short)q2; af[2].u[7] = (unsigned short)(q2 >> 16);
    } else {
        af[2].u = *(const u16x8*)(inr + 64 + sl * 8);
    }
    af[3].u = *(const u16x8*)(inr + 96 + sl * 8);
    af[4].u = *(const u16x8*)(inr + 128 + sl * 8);

    __syncthreads();   // W blob + bias visible

    f32x4 acc[4];
#pragma unroll
    for (int j = 0; j < 4; ++j) acc[j] = (f32x4){0.f, 0.f, 0.f, 0.f};
#pragma unroll
    for (int j = 0; j < 4; ++j) {
#pragma unroll
        for (int kt = 0; kt < 5; ++kt) {
            const bf16x8 bh = *(const bf16x8*)(Ws + frag_addr(j, kt, row, sl));
            acc[j] = __builtin_amdgcn_mfma_f32_16x16x32_bf16(af[kt].s, bh, acc[j], 0, 0, 0);
        }
#pragma unroll
        for (int kt = 0; kt < 5; ++kt) {
            const bf16x8 bl = *(const bf16x8*)(Ws + WHALF + frag_addr(j, kt, row, sl));
            acc[j] = __builtin_amdgcn_mfma_f32_16x16x32_bf16(af[kt].s, bl, acc[j], 0, 0, 0);
        }
    }

#pragma unroll
    for (int j = 0; j < 4; ++j) {
        const int o_l = j * 16 + row;
        const float bs = bias_l[o_l];
#pragma unroll
        for (int r = 0; r < 4; ++r) {
            const int bb = w * 16 + sl * 4 + r;
            const float sg = 1.f / (1.f + __expf(-(acc[j][r] + bs)));
            if (half == 0) {
                const float st = state[((size_t)bb * N_NODES + n) * DOUT + o_l];
                IN[((size_t)n * BATCH + bb) * INP + 2 + o_l] = f2bf_rn(sg * st);
            } else {
                Rb[((size_t)n * BATCH + bb) * DOUT + o_l] = f2bf_rn(sg);
            }
        }
    }
}

// ---------------------------------------------------------------------------
// Kernel 7: update transform + GRU output. Grid nN.
__global__ __launch_bounds__(256) void update_mfma_kernel(
    const float* __restrict__ E, const float* __restrict__ bp,
    const float* __restrict__ x, const float* __restrict__ state,
    const unsigned short* __restrict__ IN, const unsigned char* __restrict__ Wc,
    int n0, const unsigned short* __restrict__ Rb, float* __restrict__ out)
{
    const int n_l = blockIdx.x;
    const int n   = n0 + n_l;
    const int tid = threadIdx.x;

    __shared__ __align__(16) unsigned char Ws[WBLOB];
    __shared__ float bias_l[64];

    const unsigned char* src = Wc + (size_t)n_l * WBLOB;
#pragma unroll
    for (int i = 0; i < 10; ++i)
        gload_lds16(src + (tid + i * 256) * 16, Ws + (tid + i * 256) * 16);

    if (tid < 64) {
        float s = 0.f;
#pragma unroll
        for (int d = 0; d < D_EMB; ++d)
            s += E[n * D_EMB + d] * bp[d * DOUT + tid];
        bias_l[tid] = s;
    }

    const int lane = tid & 63, w = tid >> 6;
    const int row = lane & 15, sl = lane >> 4;
    const int b = w * 16 + row;
    const unsigned short* inr = IN + ((size_t)n * BATCH + b) * INP;

    afrag af[5];
    if (sl == 0) {   // kt0 sl0: x + zs k2..7
        const float2 xv = *(const float2*)(x + ((size_t)b * N_NODES + n) * DIN);
        af[0].u[0] = f2bf_rn(xv.x);
        af[0].u[1] = f2bf_rn(xv.y);
        const unsigned int* q = (const unsigned int*)((const char*)inr + 4);
        const unsigned int q0 = q[0], q1 = q[1], q2 = q[2];
        af[0].u[2] = (unsigned short)q0; af[0].u[3] = (unsigned short)(q0 >> 16);
        af[0].u[4] = (unsigned short)q1; af[0].u[5] = (unsigned short)(q1 >> 16);
        af[0].u[6] = (unsigned short)q2; af[0].u[7] = (unsigned short)(q2 >> 16);
    } else {
        af[0].u = *(const u16x8*)(inr + sl * 8);
    }
#pragma unroll
    for (int kt = 1; kt < 5; ++kt)
        af[kt].u = *(const u16x8*)(inr + kt * 32 + sl * 8);

    __syncthreads();

    f32x4 acc[4];
#pragma unroll
    for (int j = 0; j < 4; ++j) acc[j] = (f32x4){0.f, 0.f, 0.f, 0.f};
#pragma unroll
    for (int j = 0; j < 4; ++j) {
#pragma unroll
        for (int kt = 0; kt < 5; ++kt) {
            const bf16x8 bh = *(const bf16x8*)(Ws + frag_addr(j, kt, row, sl));
            acc[j] = __builtin_amdgcn_mfma_f32_16x16x32_bf16(af[kt].s, bh, acc[j], 0, 0, 0);
        }
#pragma unroll
        for (int kt = 0; kt < 5; ++kt) {
            const bf16x8 bl = *(const bf16x8*)(Ws + WHALF + frag_addr(j, kt, row, sl));
            acc[j] = __builtin_amdgcn_mfma_f32_16x16x32_bf16(af[kt].s, bl, acc[j], 0, 0, 0);
        }
    }

#pragma unroll
    for (int j = 0; j < 4; ++j) {
        const int o_l = j * 16 + row;
        const float bs = bias_l[o_l];
#pragma unroll
        for (int r = 0; r < 4; ++r) {
            const int bb = w * 16 + sl * 4 + r;
            const float hc = tanhf(acc[j][r] + bs);
            const float rr = bf2f(Rb[((size_t)n * BATCH + bb) * DOUT + o_l]);
            const float st = state[((size_t)bb * N_NODES + n) * DOUT + o_l];
            out[((size_t)bb * N_NODES + n) * DOUT + o_l] = rr * st + (1.f - rr) * hc;
        }
    }
}

// ---------------------------------------------------------------------------
extern "C" void kernel_launch(void* const* d_in, const int* in_sizes, int n_in,
                              void* d_out, int out_size, void* d_ws, size_t ws_size,
                              hipStream_t stream)
{
    const float* x  = (const float*)d_in[0];
    const float* st = (const float*)d_in[1];
    const float* E  = (const float*)d_in[2];
    const float* gw = (const float*)d_in[3];
    const float* gb = (const float*)d_in[4];
    const float* uw = (const float*)d_in[5];
    const float* ub = (const float*)d_in[6];
    float* out = (float*)d_out;

    // fixed workspace layout (85.98 MB) + adaptive weight-chunk buffer
    unsigned char* ws = (unsigned char*)d_ws;
    unsigned short* S_hi = (unsigned short*)ws;                       // 8,388,608
    unsigned short* XT   = (unsigned short*)(ws + 8388608);           // 17,825,792
    unsigned short* IN   = (unsigned short*)(ws + 26214400);          // 41,943,040
    unsigned short* Rb   = (unsigned short*)(ws + 68157440);          // 16,777,216
    float* wpTg          = (float*)(ws + 84934656);                   //    696,320
    float* wpTu          = (float*)(ws + 85630976);                   //    348,160
    unsigned char* Wc    = ws + 85979136;

    // chunk size: largest power-of-two node count whose gate blobs fit
    const size_t fixed_b = 85979136;
    int C = 64;
    const int cands[5] = {2048, 1024, 512, 256, 128};
    for (int i = 0; i < 5; ++i) {
        if (ws_size >= fixed_b + (size_t)cands[i] * (2 * WBLOB)) { C = cands[i]; break; }
    }
    const int nch = N_NODES / C;

    const int tg = D_EMB * GOUT * KPAD;
    const int tu = D_EMB * DOUT * KPAD;
    transpose_pool_kernel<<<(tg + 255) / 256, 256, 0, stream>>>(gw, wpTg, GOUT, tg);
    transpose_pool_kernel<<<(tu + 255) / 256, 256, 0, stream>>>(uw, wpTu, DOUT, tu);

    supports_kernel<<<N_NODES, 256, 0, stream>>>(E, S_hi);
    zero_tail_kernel<<<(N_NODES * BATCH * 13 + 255) / 256, 256, 0, stream>>>(IN);
    build_xt_kernel<<<dim3(N_NODES / 64, BATCH), 256, 0, stream>>>(x, st, IN, 0, XT);
    gemm_mfma_kernel<<<544, 256, 0, stream>>>(S_hi, XT, IN);

    for (int ch = 0; ch < nch; ++ch) {
        const int n0 = ch * C;
        wgen_kernel<<<dim3(10, C / 16), 256, 0, stream>>>(E, wpTg, Wc, n0, 2, GOUT);
        gate_mfma_kernel<<<dim3(C, 2), 256, 0, stream>>>(E, gb, x, st, IN, Wc, n0, Rb);
    }

    build_xt_kernel<<<dim3(N_NODES / 64, BATCH), 256, 0, stream>>>(x, st, IN, 1, XT);
    gemm_mfma_kernel<<<544, 256, 0, stream>>>(S_hi, XT, IN);

    for (int ch = 0; ch < nch; ++ch) {
        const int n0 = ch * C;
        wgen_kernel<<<dim3(5, C / 16), 256, 0, stream>>>(E, wpTu, Wc, n0, 1, DOUT);
        update_mfma_kernel<<<C, 256, 0, stream>>>(E, ub, x, st, IN, Wc, n0, Rb, out);
    }
}